// Round 1
// baseline (360.393 us; speedup 1.0000x reference)
//
#include <hip/hip_runtime.h>

// Dynamic filter layer, 'valid', stride 1:
// out[b,i,j,c] = sum_{di,dj} x[b,i+di,j+dj,c] * flow[b,i,j,di*K+dj]
// B=8, H=W=256, C=64, K=5, Ho=Wo=252. All fp32.

constexpr int B  = 8;
constexpr int H  = 256;
constexpr int W  = 256;
constexpr int C  = 64;
constexpr int K  = 5;
constexpr int Ho = H - K + 1;   // 252
constexpr int Wo = W - K + 1;   // 252
constexpr int CQ = C / 4;       // 16 float4 quads per pixel

__global__ __launch_bounds__(256) void dfl_kernel(
    const float* __restrict__ x,
    const float* __restrict__ flow,
    float* __restrict__ out)
{
    const int tid = blockIdx.x * 256 + threadIdx.x;       // one thread = one (pixel, quad)
    const int nquads = B * Ho * Wo * CQ;                  // 8,128,512
    if (tid >= nquads) return;

    const int q     = tid & (CQ - 1);                     // channel quad 0..15
    const int pixel = tid >> 4;                           // 0..508031
    const int b     = pixel / (Ho * Wo);
    const int rem   = pixel - b * (Ho * Wo);
    const int i     = rem / Wo;
    const int j     = rem - i * Wo;

    // 25 flow taps for this pixel; identical across the pixel's 16 threads
    // (same cacheline group -> L1 broadcast).
    const float* fl = flow + pixel * (K * K);
    float f[K * K];
    #pragma unroll
    for (int t = 0; t < K * K; ++t) f[t] = fl[t];

    // x base for this pixel's top-left tap, at this thread's channel quad.
    const float4* xb = (const float4*)(x + ((b * H + i) * W + j) * C) + q;

    float4 acc = make_float4(0.f, 0.f, 0.f, 0.f);
    #pragma unroll
    for (int di = 0; di < K; ++di) {
        #pragma unroll
        for (int dj = 0; dj < K; ++dj) {
            const float4 xv = xb[(di * W + dj) * CQ];
            const float  w  = f[di * K + dj];
            acc.x += xv.x * w;
            acc.y += xv.y * w;
            acc.z += xv.z * w;
            acc.w += xv.w * w;
        }
    }

    ((float4*)out)[tid] = acc;   // fully coalesced: tid*16B
}

extern "C" void kernel_launch(void* const* d_in, const int* in_sizes, int n_in,
                              void* d_out, int out_size, void* d_ws, size_t ws_size,
                              hipStream_t stream) {
    const float* x    = (const float*)d_in[0];
    const float* flow = (const float*)d_in[1];
    // d_in[2] is ksize (scalar), fixed at 5 — baked in as constexpr.
    float* out = (float*)d_out;

    const int nquads = B * Ho * Wo * CQ;          // 8,128,512
    const int grid   = (nquads + 255) / 256;      // 31,752
    dfl_kernel<<<grid, 256, 0, stream>>>(x, flow, out);
}

// Round 2
// 314.865 us; speedup vs baseline: 1.1446x; 1.1446x over previous
//
#include <hip/hip_runtime.h>

// Dynamic filter layer, 'valid', stride 1:
// out[b,i,j,c] = sum_{di,dj} x[b,i+di,j+dj,c] * flow[b,i,j,di*K+dj]
// B=8, H=W=256, C=64, K=5, Ho=Wo=252. All fp32.
//
// R1: register-block R=6 outputs along i per thread (row-sliding window).
// x loads drop 25 -> 5*(R+4)/R = 8.33 float4 per output (3x less L1 traffic),
// and each thread carries 50 independent float4 loads for latency hiding.

constexpr int B  = 8;
constexpr int H  = 256;
constexpr int W  = 256;
constexpr int C  = 64;
constexpr int K  = 5;
constexpr int Ho = H - K + 1;            // 252
constexpr int Wo = W - K + 1;            // 252
constexpr int CQ = C / 4;                // 16 float4 quads per pixel
constexpr int R  = 6;                    // outputs per thread along i (Ho % R == 0)
constexpr int SEG = Ho / R;              // 42 row segments
constexpr int JT  = 16;                  // j-pixels per block (16 j x 16 q = 256 thr)
constexpr int JB  = (Wo + JT - 1) / JT;  // 16 j blocks (last partial)

__global__ __launch_bounds__(256) void dfl_kernel(
    const float* __restrict__ x,
    const float* __restrict__ flow,
    float* __restrict__ out)
{
    const int t  = threadIdx.x;
    const int q  = t & (CQ - 1);          // channel quad 0..15
    const int jj = t >> 4;                // j within block 0..15

    int bid = blockIdx.x;
    const int jb  = bid % JB;  bid /= JB;
    const int seg = bid % SEG; bid /= SEG;
    const int b   = bid;

    const int j = jb * JT + jj;
    if (j >= Wo) return;                  // partial last j-block; no LDS, safe
    const int i0 = seg * R;

    // x quad pointer at (b, i0, j, q); row stride W*CQ quads, col stride CQ.
    const float4* xq = (const float4*)x + ((b * H + i0) * W + j) * CQ + q;
    // flow base at (b, i0, j, 0); output-row stride Wo*25 floats.
    const float*  fb = flow + ((b * Ho + i0) * Wo + j) * (K * K);

    float4 acc[R];
    #pragma unroll
    for (int ii = 0; ii < R; ++ii) acc[ii] = make_float4(0.f, 0.f, 0.f, 0.f);

    // Slide over the R+K-1 = 10 input rows this column segment touches.
    #pragma unroll
    for (int r = 0; r < R + K - 1; ++r) {
        float4 xrow[K];
        #pragma unroll
        for (int dj = 0; dj < K; ++dj)
            xrow[dj] = xq[r * (W * CQ) + dj * CQ];

        #pragma unroll
        for (int ii = 0; ii < R; ++ii) {
            const int di = r - ii;                 // tap row for output ii
            if (di < 0 || di >= K) continue;       // compile-time resolved
            const float* fp = fb + ii * (Wo * K * K) + di * K;
            #pragma unroll
            for (int dj = 0; dj < K; ++dj) {
                const float w = fp[dj];
                acc[ii].x += xrow[dj].x * w;
                acc[ii].y += xrow[dj].y * w;
                acc[ii].z += xrow[dj].z * w;
                acc[ii].w += xrow[dj].w * w;
            }
        }
    }

    float4* ob = (float4*)out + ((b * Ho + i0) * Wo + j) * CQ + q;
    #pragma unroll
    for (int ii = 0; ii < R; ++ii)
        ob[ii * (Wo * CQ)] = acc[ii];
}

extern "C" void kernel_launch(void* const* d_in, const int* in_sizes, int n_in,
                              void* d_out, int out_size, void* d_ws, size_t ws_size,
                              hipStream_t stream) {
    const float* x    = (const float*)d_in[0];
    const float* flow = (const float*)d_in[1];
    // d_in[2] is ksize (scalar), fixed at 5 — baked in as constexpr.
    float* out = (float*)d_out;

    const int grid = B * SEG * JB;        // 8 * 42 * 16 = 5376 blocks
    dfl_kernel<<<grid, 256, 0, stream>>>(x, flow, out);
}

// Round 3
// 301.814 us; speedup vs baseline: 1.1941x; 1.0432x over previous
//
#include <hip/hip_runtime.h>

// Dynamic filter layer, 'valid', stride 1:
// out[b,i,j,c] = sum_{di,dj} x[b,i+di,j+dj,c] * flow[b,i,j,di*K+dj]
// B=8, H=W=256, C=64, K=5, Ho=Wo=252. All fp32.
//
// R2: flow tile staged in LDS (coalesced cooperative load), killing the
// 150 per-thread scalar global flow loads (the dominant vmem-instr cost).
// x keeps the R=6 vertical register sliding window from R1.

constexpr int B  = 8;
constexpr int H  = 256;
constexpr int W  = 256;
constexpr int C  = 64;
constexpr int K  = 5;
constexpr int Ho = H - K + 1;            // 252
constexpr int Wo = W - K + 1;            // 252
constexpr int CQ = C / 4;                // 16 float4 quads per pixel
constexpr int R  = 6;                    // outputs per thread along i (Ho % R == 0)
constexpr int SEG = Ho / R;              // 42 row segments
constexpr int JT  = 16;                  // j-pixels per block (16 j x 16 q = 256 thr)
constexpr int JB  = (Wo + JT - 1) / JT;  // 16 j blocks (last partial)
constexpr int FP  = 36;                  // padded taps/pixel in LDS:
                                         //  - 36*4B = 144B, 16B-aligned bases
                                         //  - bank stride 36%32=4 -> jj lanes on
                                         //    banks 0/4/8/12, conflict-free

__global__ __launch_bounds__(256) void dfl_kernel(
    const float* __restrict__ x,
    const float* __restrict__ flow,
    float* __restrict__ out)
{
    __shared__ float sf[R * JT * FP];     // 13.8 KB

    const int t  = threadIdx.x;
    const int q  = t & (CQ - 1);          // channel quad 0..15
    const int jj = t >> 4;                // j within block 0..15

    int bid = blockIdx.x;
    const int jb  = bid % JB;  bid /= JB;
    const int seg = bid % SEG; bid /= SEG;
    const int b   = bid;

    const int j0 = jb * JT;
    const int j  = j0 + jj;
    const int i0 = seg * R;

    // ---- Stage flow tile: R rows x 16 pixels x 25 taps, coalesced ----
    {
        const float* src0 = flow + ((b * Ho + i0) * Wo + j0) * (K * K);
        #pragma unroll
        for (int ii = 0; ii < R; ++ii) {
            const float* src = src0 + ii * (Wo * K * K);
            #pragma unroll
            for (int s = 0; s < JT * K * K; s += 256) {
                const int e = s + t;
                if (e < JT * K * K) {
                    const int pj  = e / (K * K);
                    const int tap = e - pj * (K * K);
                    if (j0 + pj < Wo)
                        sf[(ii * JT + pj) * FP + tap] = src[e];
                }
            }
        }
    }
    __syncthreads();

    // ---- Compute: vertical sliding window over R+K-1 = 10 x rows ----
    const int jx = j < Wo ? j : Wo - 1;   // clamp for edge block (store guarded)
    const float4* xq = (const float4*)x + ((b * H + i0) * W + jx) * CQ + q;

    float4 acc[R];
    #pragma unroll
    for (int ii = 0; ii < R; ++ii) acc[ii] = make_float4(0.f, 0.f, 0.f, 0.f);

    #pragma unroll
    for (int r = 0; r < R + K - 1; ++r) {
        float4 xrow[K];
        #pragma unroll
        for (int dj = 0; dj < K; ++dj)
            xrow[dj] = xq[r * (W * CQ) + dj * CQ];

        #pragma unroll
        for (int ii = 0; ii < R; ++ii) {
            const int di = r - ii;                 // tap row for output ii
            if (di < 0 || di >= K) continue;       // compile-time resolved
            const float* fp = &sf[(ii * JT + jj) * FP + di * K];
            #pragma unroll
            for (int dj = 0; dj < K; ++dj) {
                const float w = fp[dj];
                acc[ii].x += xrow[dj].x * w;
                acc[ii].y += xrow[dj].y * w;
                acc[ii].z += xrow[dj].z * w;
                acc[ii].w += xrow[dj].w * w;
            }
        }
    }

    if (j < Wo) {
        float4* ob = (float4*)out + ((b * Ho + i0) * Wo + j) * CQ + q;
        #pragma unroll
        for (int ii = 0; ii < R; ++ii)
            ob[ii * (Wo * CQ)] = acc[ii];
    }
}

extern "C" void kernel_launch(void* const* d_in, const int* in_sizes, int n_in,
                              void* d_out, int out_size, void* d_ws, size_t ws_size,
                              hipStream_t stream) {
    const float* x    = (const float*)d_in[0];
    const float* flow = (const float*)d_in[1];
    // d_in[2] is ksize (scalar), fixed at 5 — baked in as constexpr.
    float* out = (float*)d_out;

    const int grid = B * SEG * JB;        // 8 * 42 * 16 = 5376 blocks
    dfl_kernel<<<grid, 256, 0, stream>>>(x, flow, out);
}